// Round 22
// baseline (117.696 us; speedup 1.0000x reference)
//
#include <hip/hip_runtime.h>
#include <math.h>

#define B_ 16
#define L_ 256
#define D_ 64

#define CHUNK 8                     // paired: block owns chunks p and p+16 (13 intervals)
#define WARM  5
#define NPAIR 16                    // 32 chunks -> 16 pairs; grid = 16b x 16p = 256
#define NSTEP (CHUNK + WARM)        // 13 intervals (chunk A of pair 0 uses only 8)

#define PITCH 64                    // 16 quads/slot; phys quad = dq ^ swz(slot)
#define NSLOT 63                    // slot 0 = x(t) row 63; slot 1+j = h(t-1) row j
#define FBUF  (NSLOT * PITCH)       // 4032 floats = 16.1 KB
#define LDSZ  (4 * FBUF)            // A:2 buffers + B:2 buffers = 63 KB

__device__ __forceinline__ int swz(int s) { return (s + (s >> 1)) & 7; }

// fast tanh via v_exp_f32: overflow/NaN-safe, ~1e-7 rel error (thr 1e-2)
__device__ __forceinline__ float ftanh(float x) {
    float ax = fabsf(x);
    float e  = __builtin_amdgcn_exp2f(-2.8853900818f * ax);   // e^{-2ax}
    float r  = (1.0f - e) * __builtin_amdgcn_rcpf(1.0f + e);
    return copysignf(r, x);
}

// DPP wave shifts with zero boundary fill (bound_ctrl=1).
// Safe ONLY with fully-uniform exec (R11/R15 lesson) — here all branches
// containing DPP are block-uniform.
__device__ __forceinline__ float dpp_shr1(float x) {
    int r = __builtin_amdgcn_update_dpp(0, __float_as_int(x), 0x138, 0xF, 0xF, true);
    return __int_as_float(r);
}
__device__ __forceinline__ float dpp_shl1(float x) {
    int r = __builtin_amdgcn_update_dpp(0, __float_as_int(x), 0x130, 0xF, 0xF, true);
    return __int_as_float(r);
}

// ---------------------------------------------------------------------------
// fused_layer v8 — paired-chunk ILP. R21 step was stall-dominated (VALUBusy
// 32%, step time invariant to all per-wave work reductions); one block now
// advances TWO independent chunks per barrier interval so each chain's
// latency stalls issue the other chain's instructions. Per chunk the data
// scheme is exactly v7: rows 0..31 from global x in registers (1-step
// prefetch, never vmcnt-drained thanks to the raw lgkm-only barrier);
// h(t-1) rows 0..61 + x(t) row 63 in a double-buffered swizzled LDS frame.
// Row 63 lanes stage x row 63 and their conv output is discarded.
// WARM=5 warm-up per chunk makes chunk starts exact. Row 63 -> scan63.
__global__ __launch_bounds__(1024, 1) void fused_layer(
        const float* __restrict__ X, float* __restrict__ H,
        const float* __restrict__ Wl, const float* __restrict__ bl) {
    __shared__ float lds[LDSZ];

    const int tid    = threadIdx.x;
    const int b      = blockIdx.x >> 4;
    const int p      = blockIdx.x & (NPAIR - 1);
    const int T0A    = p * CHUNK;
    const int T0B    = (p + NPAIR) * CHUNK;
    const int twA    = (T0A >= WARM) ? (T0A - WARM) : 0;
    const int twB    = T0B - WARM;                     // >= 123, always valid
    const int tendA  = T0A + CHUNK;
    const int tendB  = T0B + CHUNK;
    const int btbase = b * L_;

    const int r    = tid >> 4;                         // row 0..63
    const int l16  = tid & 15;
    const int q0   = l16;
    const int c0   = l16 << 2;
    const bool lvl0 = (r < 32);                        // wave-uniform
    const bool st63 = (r == 63);
    const int  rc   = (r < 63) ? r : 62;

    int ro[3];
#pragma unroll
    for (int ki = 0; ki < 3; ++ki) {
        const int s = 2 * rc - 64 + ki;                // 0..62 for r>=32
        const int sc = (s < 0) ? 0 : s;
        ro[ki] = sc * PITCH + ((q0 ^ swz(sc)) << 2);
    }
    const int shh = (r + 1 <= 62) ? (r + 1) : 62;
    const int hw  = shh * PITCH + ((q0 ^ swz(shh)) << 2);
    const int xw  = q0 << 2;                           // slot 0, swz(0)=0

    const bool le0  = (l16 == 0);
    const bool le15 = (l16 == 15);

    float w[9];
#pragma unroll
    for (int k = 0; k < 9; ++k) w[k] = Wl[k];
    const float bias = bl[0];
    const float4 z4 = make_float4(0.f, 0.f, 0.f, 0.f);

    for (int k = tid; k < LDSZ / 4; k += 1024)
        reinterpret_cast<float4*>(lds)[k] = z4;        // h(-1)=0 (chunk A of p=0)
    __syncthreads();

    float* curA = lds;
    float* nxtA = lds + FBUF;
    float* curB = lds + 2 * FBUF;
    float* nxtB = lds + 3 * FBUF;

    // ---- pre-loop staging for a chunk ----
    auto PRESTAGE = [&](int tw, float* cur, float4& cx0, float4& cx1,
                        float4& cx2, float4& p63) {
        if (lvl0) {
            const float* xf = X + ((size_t)(btbase + tw) << 12);
            const int cr0 = 2 * r - 1;
            if (cr0 >= 0) cx0 = *reinterpret_cast<const float4*>(xf + (cr0 << 6) + c0);
            cx1 = *reinterpret_cast<const float4*>(xf + ((cr0 + 1) << 6) + c0);
            cx2 = *reinterpret_cast<const float4*>(xf + ((cr0 + 2) << 6) + c0);
        }
        if (st63) {
            const float* xf = X + ((size_t)(btbase + tw) << 12) + (63 << 6) + c0;
            *reinterpret_cast<float4*>(cur + xw) = *reinterpret_cast<const float4*>(xf);
            const int t1 = (tw + 1 < L_) ? tw + 1 : L_ - 1;
            p63 = *reinterpret_cast<const float4*>(
                X + ((size_t)(btbase + t1) << 12) + (63 << 6) + c0);
        }
    };

    float4 cxA0 = z4, cxA1 = z4, cxA2 = z4, pA63 = z4;
    float4 cxB0 = z4, cxB1 = z4, cxB2 = z4, pB63 = z4;
    PRESTAGE(twA, curA, cxA0, cxA1, cxA2, pA63);
    PRESTAGE(twB, curB, cxB0, cxB1, cxB2, pB63);
    __syncthreads();

    // ---- one chunk sub-step (no barrier inside) ----
    auto SUBSTEP = [&](int t, int T0c, float* cur, float* nxt,
                       float4& cx0, float4& cx1, float4& cx2, float4& p63) {
        float4 nx0 = z4, nx1 = z4, nx2 = z4, n63 = z4;
        if (lvl0) {
            const int tn = (t + 1 < L_) ? t + 1 : L_ - 1;
            const float* xf = X + ((size_t)(btbase + tn) << 12);
            const int cr0 = 2 * r - 1;
            if (cr0 >= 0) nx0 = *reinterpret_cast<const float4*>(xf + (cr0 << 6) + c0);
            nx1 = *reinterpret_cast<const float4*>(xf + ((cr0 + 1) << 6) + c0);
            nx2 = *reinterpret_cast<const float4*>(xf + ((cr0 + 2) << 6) + c0);
        }
        if (st63) {
            const int t2 = (t + 2 < L_) ? t + 2 : L_ - 1;
            n63 = *reinterpret_cast<const float4*>(
                X + ((size_t)(btbase + t2) << 12) + (63 << 6) + c0);
        }

        float u0[4], u1[4], u2[4];
#pragma unroll
        for (int k = 0; k < 4; ++k) { u0[k] = 0.f; u1[k] = bias; u2[k] = 0.f; }
#pragma unroll
        for (int ki = 0; ki < 3; ++ki) {
            float g[4];
            if (lvl0) {
                const float4 o4 = (ki == 0) ? cx0 : (ki == 1) ? cx1 : cx2;
                g[0] = o4.x; g[1] = o4.y; g[2] = o4.z; g[3] = o4.w;
            } else {
                const float4 o4 = *reinterpret_cast<const float4*>(cur + ro[ki]);
                g[0] = o4.x; g[1] = o4.y; g[2] = o4.z; g[3] = o4.w;
            }
            const float wa = w[ki*3], wb = w[ki*3+1], wc = w[ki*3+2];
#pragma unroll
            for (int k = 0; k < 4; ++k) {
                u0[k] = fmaf(wa, g[k], u0[k]);
                u1[k] = fmaf(wb, g[k], u1[k]);
                u2[k] = fmaf(wc, g[k], u2[k]);
            }
        }
        const float eLr = dpp_shr1(u0[3]);
        const float eRr = dpp_shl1(u2[0]);
        const float eL  = le0  ? 0.f : eLr;
        const float eR  = le15 ? 0.f : eRr;

        const float o0 = ftanh(eL    + u1[0] + u2[1]);
        const float o1 = ftanh(u0[0] + u1[1] + u2[2]);
        const float o2 = ftanh(u0[1] + u1[2] + u2[3]);
        const float o3 = ftanh(u0[2] + u1[3] + eR);

        if (r < 63 && t >= T0c) {
            float* gd = H + (((size_t)(btbase + t)) << 12) + (r << 6) + c0;
            *reinterpret_cast<float4*>(gd) = make_float4(o0, o1, o2, o3);
        }
        if (r <= 61) {
            *reinterpret_cast<float4*>(nxt + hw) = make_float4(o0, o1, o2, o3);
        }
        if (st63) {
            *reinterpret_cast<float4*>(nxt + xw) = p63;
        }
        cx0 = nx0; cx1 = nx1; cx2 = nx2; p63 = n63;
    };

    for (int j = 0; j < NSTEP; ++j) {
        const int tA = twA + j;
        const int tB = twB + j;
        if (tA < tendA)                                // block-uniform guard
            SUBSTEP(tA, T0A, curA, nxtA, cxA0, cxA1, cxA2, pA63);
        SUBSTEP(tB, T0B, curB, nxtB, cxB0, cxB1, cxB2, pB63);
        // raw barrier: LDS-visibility only (R20-proven)
        asm volatile("s_waitcnt lgkmcnt(0)" ::: "memory");
        __builtin_amdgcn_s_barrier();
        float* tp = curA; curA = nxtA; nxtA = tp;
        tp = curB; curB = nxtB; nxtB = tp;
    }
}

// ---------------------------------------------------------------------------
// Sequential scan for row 63 (reads rows 61/62 from global, written above).
#define SDEPTH 16
__global__ void scan63(float* __restrict__ dst,
                       const float* __restrict__ src,
                       const float* __restrict__ Wl,
                       const float* __restrict__ bl) {
    const int b = blockIdx.x;
    const int j = threadIdx.x;                         // 0..63, one wave
    float w[9];
#pragma unroll
    for (int k = 0; k < 9; ++k) w[k] = Wl[k];
    const float bias = bl[0];

    const size_t ST = (size_t)D_ * D_;
    const float* s61 = src + (size_t)b * L_ * ST + 61 * 64 + j;
    const float* s62 = src + (size_t)b * L_ * ST + 62 * 64 + j;
    float*       d63 = dst + (size_t)b * L_ * ST + 63 * 64 + j;

    float s = ftanh(bias);                             // t=0: h_{-1}=0
    d63[0] = s;

    float p61[SDEPTH], p62[SDEPTH];
#pragma unroll
    for (int u = 0; u < SDEPTH; ++u) {
        p61[u] = s61[(size_t)u * ST];
        p62[u] = s62[(size_t)u * ST];
    }

    for (int t0 = 1; t0 < 256; t0 += SDEPTH) {
#pragma unroll
        for (int u = 0; u < SDEPTH; ++u) {
            const int t = t0 + u;
            if (t > 255) break;
            const float r61 = p61[u], r62 = p62[u];
            int tp = t + SDEPTH - 1;
            if (tp > 255) tp = 255;
            p61[u] = s61[(size_t)tp * ST];
            p62[u] = s62[(size_t)tp * ST];
            float l1 = dpp_shr1(r61), q1 = dpp_shl1(r61);
            float l2 = dpp_shr1(r62), q2 = dpp_shl1(r62);
            float p = bias;
            p = fmaf(w[0], l1, p); p = fmaf(w[1], r61, p); p = fmaf(w[2], q1, p);
            p = fmaf(w[3], l2, p); p = fmaf(w[4], r62, p); p = fmaf(w[5], q2, p);
            float ls = dpp_shr1(s), rs = dpp_shl1(s);
            float z = fmaf(w[6], ls, fmaf(w[7], s, fmaf(w[8], rs, p)));
            s = ftanh(z);
            d63[(size_t)t * ST] = s;
        }
    }
}

extern "C" void kernel_launch(void* const* d_in, const int* in_sizes, int n_in,
                              void* d_out, int out_size, void* d_ws, size_t ws_size,
                              hipStream_t stream) {
    const float* x    = (const float*)d_in[0];   // (B,L,D,D)
    const float* W    = (const float*)d_in[1];   // (2,1,1,3,3)
    const float* bias = (const float*)d_in[2];   // (2,)
    float* out = (float*)d_out;
    float* h1  = (float*)d_ws;

    for (int l = 0; l < 2; ++l) {
        const float* X  = (l == 0) ? x  : h1;
        float*       H  = (l == 0) ? h1 : out;
        fused_layer<<<B_ * NPAIR, 1024, 0, stream>>>(X, H, W + l * 9, bias + l);
        scan63<<<B_, 64, 0, stream>>>(H, H, W + l * 9, bias + l);
    }
}